// Round 4
// baseline (303.859 us; speedup 1.0000x reference)
//
#include <hip/hip_runtime.h>
#include <hip/hip_bf16.h>
#include <cstdint>

#define C_DIM 1024
#define L_DIM 2048
#define N_DIM 4
#define M_DIM (N_DIM * L_DIM)   // 8192

typedef __attribute__((ext_vector_type(8))) short frag8;   // 8 bf16 = 4 VGPRs
typedef __attribute__((ext_vector_type(4))) float f32x4;

// ---- staging helpers: load 8 source elements -> 8 bf16 in LDS ----
struct Ld8f { float4 a, b; };
struct Ld8b { int4 a; };
__device__ __forceinline__ Ld8f ld8(const float* p) {
  return { *(const float4*)p, *(const float4*)(p + 4) };
}
__device__ __forceinline__ Ld8b ld8(const __hip_bfloat16* p) {
  return { *(const int4*)p };
}
__device__ __forceinline__ void st8(__hip_bfloat16* l, const Ld8f& v) {
  union { __hip_bfloat16 h[8]; int4 q; } u;
  u.h[0] = __float2bfloat16(v.a.x); u.h[1] = __float2bfloat16(v.a.y);
  u.h[2] = __float2bfloat16(v.a.z); u.h[3] = __float2bfloat16(v.a.w);
  u.h[4] = __float2bfloat16(v.b.x); u.h[5] = __float2bfloat16(v.b.y);
  u.h[6] = __float2bfloat16(v.b.z); u.h[7] = __float2bfloat16(v.b.w);
  *(int4*)l = u.q;
}
__device__ __forceinline__ void st8(__hip_bfloat16* l, const Ld8b& v) {
  *(int4*)l = v.a;
}

__device__ __forceinline__ void store_out(float* Y, size_t idx, float v) { Y[idx] = v; }
__device__ __forceinline__ void store_out(__hip_bfloat16* Y, size_t idx, float v) {
  Y[idx] = __float2bfloat16(v);
}

// Y[M,N] = X[M,K] @ W[N,K]^T + bias. W,bias fp32; X fp32 or bf16; Y fp32 or bf16.
// 128x128 tile, BK=32, 256 threads (4 waves, each 64x64 = 4x4 MFMA tiles).
template <typename TX, typename TY>
__global__ __launch_bounds__(256, 2)
void gemm_nt(const TX* __restrict__ X,
             const float* __restrict__ W,
             const float* __restrict__ bias,
             TY* __restrict__ Y,
             int M, int N, int K)
{
  __shared__ __hip_bfloat16 As[128 * 32];   // 8 KB, row-major [row][k], row stride 32
  __shared__ __hip_bfloat16 Bs[128 * 32];   // 8 KB
  const int tid  = threadIdx.x;
  const int lane = tid & 63;
  const int wave = tid >> 6;
  const int bm = blockIdx.x * 128;
  const int bn = blockIdx.y * 128;
  const int wr = (wave >> 1) * 64;
  const int wc = (wave & 1) * 64;

  // staging addressing: thread t covers rows (t>>2) and (t>>2)+64, k-chunk (t&3)*8
  const int srow  = tid >> 2;       // 0..63
  const int skoff = (tid & 3) * 8;  // 0,8,16,24 (elements)

  f32x4 acc[4][4] = {};

  const TX*    gA0 = X + (size_t)(bm + srow) * K + skoff;
  const TX*    gA1 = X + (size_t)(bm + 64 + srow) * K + skoff;
  const float* gB0 = W + (size_t)(bn + srow) * K + skoff;
  const float* gB1 = W + (size_t)(bn + 64 + srow) * K + skoff;

  const int arow  = lane & 15;          // m (or n) within a 16-tile
  const int akoff = (lane >> 4) * 8;    // k fragment base

  for (int k0 = 0; k0 < K; k0 += 32) {
    // global -> regs before the barrier (latency overlap)
    const auto va0 = ld8(gA0 + k0);
    const auto va1 = ld8(gA1 + k0);
    const auto vb0 = ld8(gB0 + k0);
    const auto vb1 = ld8(gB1 + k0);

    __syncthreads();   // previous iteration's ds_reads complete before overwrite

    st8(&As[srow * 32 + skoff],        va0);
    st8(&As[(64 + srow) * 32 + skoff], va1);
    st8(&Bs[srow * 32 + skoff],        vb0);
    st8(&Bs[(64 + srow) * 32 + skoff], vb1);

    __syncthreads();

    frag8 a[4], b[4];
#pragma unroll
    for (int i = 0; i < 4; i++)
      a[i] = *(const frag8*)&As[(wr + i * 16 + arow) * 32 + akoff];
#pragma unroll
    for (int j = 0; j < 4; j++)
      b[j] = *(const frag8*)&Bs[(wc + j * 16 + arow) * 32 + akoff];
#pragma unroll
    for (int i = 0; i < 4; i++)
#pragma unroll
      for (int j = 0; j < 4; j++)
        acc[i][j] = __builtin_amdgcn_mfma_f32_16x16x32_bf16(a[i], b[j], acc[i][j], 0, 0, 0);
  }

  // epilogue: C/D layout col=lane&15, row=(lane>>4)*4+r  [measured m89/m91]
#pragma unroll
  for (int i = 0; i < 4; i++) {
#pragma unroll
    for (int j = 0; j < 4; j++) {
      const int col = bn + wc + j * 16 + (lane & 15);
      const float bv = bias[col];
#pragma unroll
      for (int r = 0; r < 4; r++) {
        const int row = bm + wr + i * 16 + (lane >> 4) * 4 + r;
        store_out(Y, (size_t)row * N + col, acc[i][j][r] + bv);
      }
    }
  }
}

// One block per (n,l). dwconv(k=3,pad=1) -> LN -> GELU(exact) -> offset/mask
// heads -> softmax -> bilinear gather from x_proj (bf16) -> sampled (bf16, ws).
// All inputs fp32; internal math fp32.
__global__ __launch_bounds__(256)
void mid_fused(const float* __restrict__ x,
               const float* __restrict__ dw_w,
               const float* __restrict__ dw_b,
               const float* __restrict__ ln_g,
               const float* __restrict__ ln_b,
               const float* __restrict__ Wo,
               const float* __restrict__ bo,
               const float* __restrict__ Wm,
               const float* __restrict__ bmb,
               const __hip_bfloat16* __restrict__ xp,
               __hip_bfloat16* __restrict__ smp)
{
  const int row  = blockIdx.x;
  const int n    = row >> 11;     // / L_DIM
  const int l    = row & (L_DIM - 1);
  const int tid  = threadIdx.x;
  const int lane = tid & 63;
  const int wave = tid >> 6;

  const float* xr = x + (size_t)row * C_DIM;

  // depthwise conv, 4 channels/thread (strided for coalescing)
  float v[4];
#pragma unroll
  for (int j = 0; j < 4; j++) {
    const int c = tid + j * 256;
    const float xm = (l > 0)         ? xr[c - C_DIM] : 0.f;
    const float x0 = xr[c];
    const float xq = (l < L_DIM - 1) ? xr[c + C_DIM] : 0.f;
    v[j] = xm * dw_w[c * 3] + x0 * dw_w[c * 3 + 1] + xq * dw_w[c * 3 + 2] + dw_b[c];
  }

  // LayerNorm stats
  float s1 = v[0] + v[1] + v[2] + v[3];
  float s2 = v[0] * v[0] + v[1] * v[1] + v[2] * v[2] + v[3] * v[3];
#pragma unroll
  for (int o = 32; o > 0; o >>= 1) { s1 += __shfl_down(s1, o); s2 += __shfl_down(s2, o); }
  __shared__ float rs1[4], rs2[4];
  if (lane == 0) { rs1[wave] = s1; rs2[wave] = s2; }
  __syncthreads();
  const float fs1 = rs1[0] + rs1[1] + rs1[2] + rs1[3];
  const float fs2 = rs2[0] + rs2[1] + rs2[2] + rs2[3];
  const float mu   = fs1 * (1.f / C_DIM);
  const float var  = fs2 * (1.f / C_DIM) - mu * mu;
  const float rstd = rsqrtf(var + 1e-5f);

  // LN + exact GELU
  float g[4];
#pragma unroll
  for (int j = 0; j < 4; j++) {
    const int c = tid + j * 256;
    const float t = (v[j] - mu) * rstd * ln_g[c] + ln_b[c];
    g[j] = 0.5f * t * (1.f + erff(t * 0.70710678118654752f));
  }

  // offset/mask head partial dots
  float po[7] = {0, 0, 0, 0, 0, 0, 0}, pm[7] = {0, 0, 0, 0, 0, 0, 0};
#pragma unroll
  for (int j = 0; j < 4; j++) {
    const int c = tid + j * 256;
#pragma unroll
    for (int k = 0; k < 7; k++) {
      po[k] += g[j] * Wo[k * C_DIM + c];
      pm[k] += g[j] * Wm[k * C_DIM + c];
    }
  }
#pragma unroll
  for (int k = 0; k < 7; k++)
#pragma unroll
    for (int o = 32; o > 0; o >>= 1) { po[k] += __shfl_down(po[k], o); pm[k] += __shfl_down(pm[k], o); }

  __shared__ float hro[4][7], hrm[4][7];
  if (lane == 0)
    for (int k = 0; k < 7; k++) { hro[wave][k] = po[k]; hrm[wave][k] = pm[k]; }
  __syncthreads();

  __shared__ float wf_s[7], wc_s[7];
  __shared__ int   pf_s[7], pc_s[7];
  if (tid == 0) {
    float off[7], lg[7], mx = -1e30f;
    for (int k = 0; k < 7; k++) {
      off[k] = (hro[0][k] + hro[1][k] + hro[2][k] + hro[3][k] + bo[k]) * 2.0f;
      lg[k]  =  hrm[0][k] + hrm[1][k] + hrm[2][k] + hrm[3][k] + bmb[k];
      mx = fmaxf(mx, lg[k]);
    }
    float e[7], se = 0.f;
    for (int k = 0; k < 7; k++) { e[k] = expf(lg[k] - mx); se += e[k]; }
    const float inv = 1.f / se;
    for (int k = 0; k < 7; k++) {
      const float msk = e[k] * inv;
      const float ap  = (float)l + (float)(k - 3) + off[k];
      const float apc = fminf(fmaxf(ap, 0.f), (float)(L_DIM - 1));
      int pf = (int)apc;                       // apc >= 0 -> trunc == floor
      int pc = pf + 1; if (pc > L_DIM - 1) pc = L_DIM - 1;
      const float wcl   = apc - (float)pf;
      const float valid = (ap < 0.f || ap > (float)(L_DIM - 1)) ? 0.f : 1.f;
      wf_s[k] = (1.f - wcl) * valid * msk;
      wc_s[k] = wcl * valid * msk;
      pf_s[k] = pf; pc_s[k] = pc;
    }
  }
  __syncthreads();

  // gather + blend, mask folded into weights
  const __hip_bfloat16* xpn = xp + ((size_t)n * L_DIM) * C_DIM;
  __hip_bfloat16* so = smp + (size_t)row * C_DIM;
#pragma unroll
  for (int j = 0; j < 4; j++) {
    const int c = tid + j * 256;
    float a = 0.f;
#pragma unroll
    for (int k = 0; k < 7; k++) {
      a += wf_s[k] * (float)xpn[(size_t)pf_s[k] * C_DIM + c];
      a += wc_s[k] * (float)xpn[(size_t)pc_s[k] * C_DIM + c];
    }
    so[c] = __float2bfloat16(a);
  }
}

extern "C" void kernel_launch(void* const* d_in, const int* in_sizes, int n_in,
                              void* d_out, int out_size, void* d_ws, size_t ws_size,
                              hipStream_t stream)
{
  const float* x    = (const float*)d_in[0];
  const float* Wi   = (const float*)d_in[1];
  const float* bi   = (const float*)d_in[2];
  const float* dw_w = (const float*)d_in[3];
  const float* dw_b = (const float*)d_in[4];
  const float* ln_g = (const float*)d_in[5];
  const float* ln_b = (const float*)d_in[6];
  const float* Wo   = (const float*)d_in[7];
  const float* bo   = (const float*)d_in[8];
  const float* Wm   = (const float*)d_in[9];
  const float* bm   = (const float*)d_in[10];
  const float* Wout = (const float*)d_in[11];
  const float* bout = (const float*)d_in[12];
  float* out = (float*)d_out;          // reference output dtype is float32

  __hip_bfloat16* xp  = (__hip_bfloat16*)d_ws;                  // x_proj: 16 MB
  __hip_bfloat16* smp = xp + (size_t)M_DIM * C_DIM;             // sampled: 16 MB

  dim3 gg(M_DIM / 128, C_DIM / 128);   // 64 x 8 = 512 blocks
  gemm_nt<float, __hip_bfloat16><<<gg, 256, 0, stream>>>(x, Wi, bi, xp, M_DIM, C_DIM, C_DIM);
  mid_fused<<<M_DIM, 256, 0, stream>>>(x, dw_w, dw_b, ln_g, ln_b, Wo, bo, Wm, bm, xp, smp);
  gemm_nt<__hip_bfloat16, float><<<gg, 256, 0, stream>>>(smp, Wout, bout, out, M_DIM, C_DIM, C_DIM);
}

// Round 5
// 213.029 us; speedup vs baseline: 1.4264x; 1.4264x over previous
//
#include <hip/hip_runtime.h>
#include <hip/hip_bf16.h>
#include <cstdint>

#define C_DIM 1024
#define L_DIM 2048
#define N_DIM 4
#define M_DIM (N_DIM * L_DIM)   // 8192

typedef __attribute__((ext_vector_type(8))) short frag8;   // 8 bf16 = 4 VGPRs
typedef __attribute__((ext_vector_type(4))) float f32x4;

// ---------------- helpers ----------------
__device__ __forceinline__ void gl_lds16(const void* g, void* l) {
  __builtin_amdgcn_global_load_lds((const __attribute__((address_space(1))) void*)g,
                                   (__attribute__((address_space(3))) void*)l,
                                   16, 0, 0);
}
__device__ __forceinline__ void store_out(float* Y, size_t idx, float v) { Y[idx] = v; }
__device__ __forceinline__ void store_out(__hip_bfloat16* Y, size_t idx, float v) {
  Y[idx] = __float2bfloat16(v);
}
__device__ __forceinline__ float4 ldbf4(const __hip_bfloat16* p) {
  union { short4 s; __hip_bfloat16 h[4]; } u; u.s = *(const short4*)p;
  return make_float4((float)u.h[0], (float)u.h[1], (float)u.h[2], (float)u.h[3]);
}
__device__ __forceinline__ void stbf4(__hip_bfloat16* p, float4 v) {
  union { short4 s; __hip_bfloat16 h[4]; } u;
  u.h[0] = __float2bfloat16(v.x); u.h[1] = __float2bfloat16(v.y);
  u.h[2] = __float2bfloat16(v.z); u.h[3] = __float2bfloat16(v.w);
  *(short4*)p = u.s;
}

// fp32 -> bf16 bulk convert, 8 elems/thread (sizes are multiples of 8)
__global__ __launch_bounds__(256)
void cvt_f32_bf16(const float* __restrict__ in, __hip_bfloat16* __restrict__ out, int n8) {
  const int i = blockIdx.x * 256 + threadIdx.x;
  if (i >= n8) return;
  const float4 a = *(const float4*)(in + (size_t)i * 8);
  const float4 b = *(const float4*)(in + (size_t)i * 8 + 4);
  union { __hip_bfloat16 h[8]; int4 q; } u;
  u.h[0] = __float2bfloat16(a.x); u.h[1] = __float2bfloat16(a.y);
  u.h[2] = __float2bfloat16(a.z); u.h[3] = __float2bfloat16(a.w);
  u.h[4] = __float2bfloat16(b.x); u.h[5] = __float2bfloat16(b.y);
  u.h[6] = __float2bfloat16(b.z); u.h[7] = __float2bfloat16(b.w);
  *(int4*)(out + (size_t)i * 8) = u.q;
}

// ---------------- GEMM, m97 path: bf16 A/B via global_load_lds ----------------
// Y[M,N] = X[M,K] @ W[N,K]^T + bias. 128x128 tile, BK=32, 256 threads.
template <typename TY>
__global__ __launch_bounds__(256, 2)
void gemm_lds(const __hip_bfloat16* __restrict__ X,
              const __hip_bfloat16* __restrict__ W,
              const float* __restrict__ bias,
              TY* __restrict__ Y, int M, int N, int K)
{
  __shared__ __hip_bfloat16 As[128 * 32];
  __shared__ __hip_bfloat16 Bs[128 * 32];
  const int tid  = threadIdx.x;
  const int lane = tid & 63;
  const int wave = tid >> 6;
  const int bm = blockIdx.x * 128;
  const int bn = blockIdx.y * 128;
  const int wr = (wave >> 1) * 64;
  const int wc = (wave & 1) * 64;
  const int srow  = tid >> 2;       // 0..63
  const int skoff = (tid & 3) * 8;  // elements

  f32x4 acc[4][4] = {};
  const __hip_bfloat16* gA0 = X + (size_t)(bm + srow) * K + skoff;
  const __hip_bfloat16* gA1 = X + (size_t)(bm + 64 + srow) * K + skoff;
  const __hip_bfloat16* gB0 = W + (size_t)(bn + srow) * K + skoff;
  const __hip_bfloat16* gB1 = W + (size_t)(bn + 64 + srow) * K + skoff;

  const int arow  = lane & 15;
  const int akoff = (lane >> 4) * 8;

  for (int k0 = 0; k0 < K; k0 += 32) {
    // LDS dest byte = tid*16: wave-uniform base + lane*16 (m97 constraint)
    gl_lds16(gA0 + k0, &As[tid * 8]);
    gl_lds16(gA1 + k0, &As[2048 + tid * 8]);
    gl_lds16(gB0 + k0, &Bs[tid * 8]);
    gl_lds16(gB1 + k0, &Bs[2048 + tid * 8]);
    __syncthreads();   // compiler emits vmcnt(0) drain before s_barrier

    frag8 a[4], b[4];
#pragma unroll
    for (int i = 0; i < 4; i++)
      a[i] = *(const frag8*)&As[(wr + i * 16 + arow) * 32 + akoff];
#pragma unroll
    for (int j = 0; j < 4; j++)
      b[j] = *(const frag8*)&Bs[(wc + j * 16 + arow) * 32 + akoff];
#pragma unroll
    for (int i = 0; i < 4; i++)
#pragma unroll
      for (int j = 0; j < 4; j++)
        acc[i][j] = __builtin_amdgcn_mfma_f32_16x16x32_bf16(a[i], b[j], acc[i][j], 0, 0, 0);
    __syncthreads();   // all waves' ds_reads done before next overwrite
  }

#pragma unroll
  for (int i = 0; i < 4; i++)
#pragma unroll
    for (int j = 0; j < 4; j++) {
      const int col = bn + wc + j * 16 + (lane & 15);
      const float bv = bias[col];
#pragma unroll
      for (int r = 0; r < 4; r++) {
        const int row = bm + wr + i * 16 + (lane >> 4) * 4 + r;
        store_out(Y, (size_t)row * N + col, acc[i][j][r] + bv);
      }
    }
}

// ---------------- fallback GEMM (round-3, register staging, fp32/bf16 X, fp32 W) ----
struct Ld8f { float4 a, b; };
struct Ld8b { int4 a; };
__device__ __forceinline__ Ld8f ld8(const float* p) {
  return { *(const float4*)p, *(const float4*)(p + 4) };
}
__device__ __forceinline__ Ld8b ld8(const __hip_bfloat16* p) { return { *(const int4*)p }; }
__device__ __forceinline__ void st8(__hip_bfloat16* l, const Ld8f& v) {
  union { __hip_bfloat16 h[8]; int4 q; } u;
  u.h[0] = __float2bfloat16(v.a.x); u.h[1] = __float2bfloat16(v.a.y);
  u.h[2] = __float2bfloat16(v.a.z); u.h[3] = __float2bfloat16(v.a.w);
  u.h[4] = __float2bfloat16(v.b.x); u.h[5] = __float2bfloat16(v.b.y);
  u.h[6] = __float2bfloat16(v.b.z); u.h[7] = __float2bfloat16(v.b.w);
  *(int4*)l = u.q;
}
__device__ __forceinline__ void st8(__hip_bfloat16* l, const Ld8b& v) { *(int4*)l = v.a; }

template <typename TX, typename TY>
__global__ __launch_bounds__(256, 2)
void gemm_nt(const TX* __restrict__ X, const float* __restrict__ W,
             const float* __restrict__ bias, TY* __restrict__ Y, int M, int N, int K)
{
  __shared__ __hip_bfloat16 As[128 * 32];
  __shared__ __hip_bfloat16 Bs[128 * 32];
  const int tid  = threadIdx.x;
  const int lane = tid & 63;
  const int wave = tid >> 6;
  const int bm = blockIdx.x * 128;
  const int bn = blockIdx.y * 128;
  const int wr = (wave >> 1) * 64;
  const int wc = (wave & 1) * 64;
  const int srow  = tid >> 2;
  const int skoff = (tid & 3) * 8;

  f32x4 acc[4][4] = {};
  const TX*    gA0 = X + (size_t)(bm + srow) * K + skoff;
  const TX*    gA1 = X + (size_t)(bm + 64 + srow) * K + skoff;
  const float* gB0 = W + (size_t)(bn + srow) * K + skoff;
  const float* gB1 = W + (size_t)(bn + 64 + srow) * K + skoff;
  const int arow  = lane & 15;
  const int akoff = (lane >> 4) * 8;

  for (int k0 = 0; k0 < K; k0 += 32) {
    const auto va0 = ld8(gA0 + k0);
    const auto va1 = ld8(gA1 + k0);
    const auto vb0 = ld8(gB0 + k0);
    const auto vb1 = ld8(gB1 + k0);
    __syncthreads();
    st8(&As[srow * 32 + skoff],        va0);
    st8(&As[(64 + srow) * 32 + skoff], va1);
    st8(&Bs[srow * 32 + skoff],        vb0);
    st8(&Bs[(64 + srow) * 32 + skoff], vb1);
    __syncthreads();

    frag8 a[4], b[4];
#pragma unroll
    for (int i = 0; i < 4; i++)
      a[i] = *(const frag8*)&As[(wr + i * 16 + arow) * 32 + akoff];
#pragma unroll
    for (int j = 0; j < 4; j++)
      b[j] = *(const frag8*)&Bs[(wc + j * 16 + arow) * 32 + akoff];
#pragma unroll
    for (int i = 0; i < 4; i++)
#pragma unroll
      for (int j = 0; j < 4; j++)
        acc[i][j] = __builtin_amdgcn_mfma_f32_16x16x32_bf16(a[i], b[j], acc[i][j], 0, 0, 0);
  }
#pragma unroll
  for (int i = 0; i < 4; i++)
#pragma unroll
    for (int j = 0; j < 4; j++) {
      const int col = bn + wc + j * 16 + (lane & 15);
      const float bv = bias[col];
#pragma unroll
      for (int r = 0; r < 4; r++) {
        const int row = bm + wr + i * 16 + (lane >> 4) * 4 + r;
        store_out(Y, (size_t)row * N + col, acc[i][j][r] + bv);
      }
    }
}

// ---------------- mid kernel v2: one WAVE per (n,l) row, no barriers ----------------
// dwconv(k=3) -> LN -> GELU(exact) -> head dots (butterfly reduce) ->
// per-lane softmax -> bilinear gather from xp (bf16) -> smp (bf16).
__global__ __launch_bounds__(256)
void mid_fused_v2(const float* __restrict__ x,
                  const float* __restrict__ dw_w, const float* __restrict__ dw_b,
                  const float* __restrict__ ln_g, const float* __restrict__ ln_b,
                  const float* __restrict__ Wo,   const float* __restrict__ bo,
                  const float* __restrict__ Wm,   const float* __restrict__ bmb,
                  const __hip_bfloat16* __restrict__ xp,
                  __hip_bfloat16* __restrict__ smp)
{
  // XCD-contiguous swizzle: dispatch i -> XCD i%8 (heuristic); give each XCD
  // a contiguous 1024-row range so gather rows stay in its L2.
  const int b    = blockIdx.x;
  const int bs   = (b & 7) * 256 + (b >> 3);
  const int wid  = threadIdx.x >> 6;
  const int lane = threadIdx.x & 63;
  const int row  = bs * 4 + wid;
  const int l    = row & (L_DIM - 1);
  const int n    = row >> 11;

  const float* xr = x + (size_t)row * C_DIM;

  // channels per lane: c = j*256 + lane*4 + t  (t=0..3) — float4, fully coalesced
  float4 v[4];
#pragma unroll
  for (int j = 0; j < 4; j++) {
    const int c4 = j * 256 + lane * 4;
    const float4 x0 = *(const float4*)(xr + c4);
    float4 xm = make_float4(0.f, 0.f, 0.f, 0.f);
    float4 xq = make_float4(0.f, 0.f, 0.f, 0.f);
    if (l > 0)         xm = *(const float4*)(xr + c4 - C_DIM);
    if (l < L_DIM - 1) xq = *(const float4*)(xr + c4 + C_DIM);
    // taps for channels c4..c4+3: 12 consecutive floats at dw_w + c4*3 (16B-aligned)
    const float4 w0 = *(const float4*)(dw_w + (size_t)c4 * 3);
    const float4 w1 = *(const float4*)(dw_w + (size_t)c4 * 3 + 4);
    const float4 w2 = *(const float4*)(dw_w + (size_t)c4 * 3 + 8);
    const float4 bb = *(const float4*)(dw_b + c4);
    v[j].x = xm.x * w0.x + x0.x * w0.y + xq.x * w0.z + bb.x;
    v[j].y = xm.y * w0.w + x0.y * w1.x + xq.y * w1.y + bb.y;
    v[j].z = xm.z * w1.z + x0.z * w1.w + xq.z * w2.x + bb.z;
    v[j].w = xm.w * w2.y + x0.w * w2.z + xq.w * w2.w + bb.w;
  }

  // LayerNorm stats: butterfly so every lane gets the totals
  float s1 = 0.f, s2 = 0.f;
#pragma unroll
  for (int j = 0; j < 4; j++) {
    s1 += v[j].x + v[j].y + v[j].z + v[j].w;
    s2 += v[j].x * v[j].x + v[j].y * v[j].y + v[j].z * v[j].z + v[j].w * v[j].w;
  }
#pragma unroll
  for (int m = 1; m < 64; m <<= 1) { s1 += __shfl_xor(s1, m); s2 += __shfl_xor(s2, m); }
  const float mu   = s1 * (1.f / C_DIM);
  const float var  = s2 * (1.f / C_DIM) - mu * mu;
  const float rstd = rsqrtf(var + 1e-5f);

  // LN + exact GELU
  float4 g[4];
#pragma unroll
  for (int j = 0; j < 4; j++) {
    const int c4 = j * 256 + lane * 4;
    const float4 gg = *(const float4*)(ln_g + c4);
    const float4 bb = *(const float4*)(ln_b + c4);
    float t;
    t = (v[j].x - mu) * rstd * gg.x + bb.x; g[j].x = 0.5f * t * (1.f + erff(t * 0.70710678f));
    t = (v[j].y - mu) * rstd * gg.y + bb.y; g[j].y = 0.5f * t * (1.f + erff(t * 0.70710678f));
    t = (v[j].z - mu) * rstd * gg.z + bb.z; g[j].z = 0.5f * t * (1.f + erff(t * 0.70710678f));
    t = (v[j].w - mu) * rstd * gg.w + bb.w; g[j].w = 0.5f * t * (1.f + erff(t * 0.70710678f));
  }

  // offset / mask head dot-products
  float po[7] = {0,0,0,0,0,0,0}, pm[7] = {0,0,0,0,0,0,0};
#pragma unroll
  for (int k = 0; k < 7; k++) {
#pragma unroll
    for (int j = 0; j < 4; j++) {
      const int c4 = j * 256 + lane * 4;
      const float4 wo = *(const float4*)(Wo + (size_t)k * C_DIM + c4);
      const float4 wm = *(const float4*)(Wm + (size_t)k * C_DIM + c4);
      po[k] += g[j].x * wo.x + g[j].y * wo.y + g[j].z * wo.z + g[j].w * wo.w;
      pm[k] += g[j].x * wm.x + g[j].y * wm.y + g[j].z * wm.z + g[j].w * wm.w;
    }
  }
#pragma unroll
  for (int k = 0; k < 7; k++)
#pragma unroll
    for (int m = 1; m < 64; m <<= 1) {
      po[k] += __shfl_xor(po[k], m);
      pm[k] += __shfl_xor(pm[k], m);
    }

  // softmax + sampling weights, computed redundantly by every lane (no serial section)
  float lg[7], mx = -1e30f;
#pragma unroll
  for (int k = 0; k < 7; k++) { lg[k] = pm[k] + bmb[k]; mx = fmaxf(mx, lg[k]); }
  float se = 0.f, e[7];
#pragma unroll
  for (int k = 0; k < 7; k++) { e[k] = __expf(lg[k] - mx); se += e[k]; }
  const float inv = 1.f / se;

  float wf[7], wcl[7]; int pf[7], pc[7];
#pragma unroll
  for (int k = 0; k < 7; k++) {
    const float msk = e[k] * inv;
    const float off = (po[k] + bo[k]) * 2.0f;
    const float ap  = (float)l + (float)(k - 3) + off;
    const float apc = fminf(fmaxf(ap, 0.f), (float)(L_DIM - 1));
    int f = (int)apc;
    int c = f + 1; if (c > L_DIM - 1) c = L_DIM - 1;
    const float w1  = apc - (float)f;
    const float val = (ap < 0.f || ap > (float)(L_DIM - 1)) ? 0.f : 1.f;
    wf[k] = (1.f - w1) * val * msk;
    wcl[k] = w1 * val * msk;
    pf[k] = f; pc[k] = c;
  }

  // gather + blend
  const __hip_bfloat16* xpn = xp + ((size_t)n * L_DIM) * C_DIM;
  __hip_bfloat16* so = smp + (size_t)row * C_DIM;
#pragma unroll
  for (int j = 0; j < 4; j++) {
    const int c4 = j * 256 + lane * 4;
    float4 a = make_float4(0.f, 0.f, 0.f, 0.f);
#pragma unroll
    for (int k = 0; k < 7; k++) {
      const float4 vf = ldbf4(xpn + (size_t)pf[k] * C_DIM + c4);
      const float4 vc = ldbf4(xpn + (size_t)pc[k] * C_DIM + c4);
      a.x += wf[k] * vf.x + wcl[k] * vc.x;
      a.y += wf[k] * vf.y + wcl[k] * vc.y;
      a.z += wf[k] * vf.z + wcl[k] * vc.z;
      a.w += wf[k] * vf.w + wcl[k] * vc.w;
    }
    stbf4(so + c4, a);
  }
}

// ---------------- host ----------------
extern "C" void kernel_launch(void* const* d_in, const int* in_sizes, int n_in,
                              void* d_out, int out_size, void* d_ws, size_t ws_size,
                              hipStream_t stream)
{
  const float* x    = (const float*)d_in[0];
  const float* Wi   = (const float*)d_in[1];
  const float* bi   = (const float*)d_in[2];
  const float* dw_w = (const float*)d_in[3];
  const float* dw_b = (const float*)d_in[4];
  const float* ln_g = (const float*)d_in[5];
  const float* ln_b = (const float*)d_in[6];
  const float* Wo   = (const float*)d_in[7];
  const float* bo   = (const float*)d_in[8];
  const float* Wm   = (const float*)d_in[9];
  const float* bm   = (const float*)d_in[10];
  const float* Wout = (const float*)d_in[11];
  const float* bout = (const float*)d_in[12];
  float* out = (float*)d_out;

  const size_t XE = (size_t)M_DIM * C_DIM;        // 8,388,608 elems
  const size_t WE = (size_t)C_DIM * C_DIM;        // 1,048,576 elems
  char* wsb = (char*)d_ws;
  __hip_bfloat16* xp    = (__hip_bfloat16*)wsb;                    // 16 MB
  __hip_bfloat16* smp   = (__hip_bfloat16*)(wsb + XE * 2);         // 16 MB
  __hip_bfloat16* Wib   = (__hip_bfloat16*)(wsb + XE * 4);         // 2 MB
  __hip_bfloat16* Woutb = (__hip_bfloat16*)(wsb + XE * 4 + WE * 2);// 2 MB
  __hip_bfloat16* xb    = (__hip_bfloat16*)(wsb + XE * 4 + WE * 4);// 16 MB

  const size_t need_w2   = XE * 4 + WE * 4;            // 37,748,736
  const size_t need_full = need_w2 + XE * 2;           // 54,525,952

  dim3 gg(M_DIM / 128, C_DIM / 128);   // 64 x 8

  if (ws_size >= need_full) {
    cvt_f32_bf16<<<(int)(XE / 8 / 256), 256, 0, stream>>>(x, xb, (int)(XE / 8));
    cvt_f32_bf16<<<(int)(WE / 8 / 256), 256, 0, stream>>>(Wi, Wib, (int)(WE / 8));
    cvt_f32_bf16<<<(int)(WE / 8 / 256), 256, 0, stream>>>(Wout, Woutb, (int)(WE / 8));
    gemm_lds<__hip_bfloat16><<<gg, 256, 0, stream>>>(xb, Wib, bi, xp, M_DIM, C_DIM, C_DIM);
    mid_fused_v2<<<M_DIM / 4, 256, 0, stream>>>(x, dw_w, dw_b, ln_g, ln_b, Wo, bo, Wm, bm, xp, smp);
    gemm_lds<float><<<gg, 256, 0, stream>>>(smp, Woutb, bout, out, M_DIM, C_DIM, C_DIM);
  } else if (ws_size >= need_w2) {
    cvt_f32_bf16<<<(int)(WE / 8 / 256), 256, 0, stream>>>(Wout, Woutb, (int)(WE / 8));
    gemm_nt<float, __hip_bfloat16><<<gg, 256, 0, stream>>>(x, Wi, bi, xp, M_DIM, C_DIM, C_DIM);
    mid_fused_v2<<<M_DIM / 4, 256, 0, stream>>>(x, dw_w, dw_b, ln_g, ln_b, Wo, bo, Wm, bm, xp, smp);
    gemm_lds<float><<<gg, 256, 0, stream>>>(smp, Woutb, bout, out, M_DIM, C_DIM, C_DIM);
  } else {
    gemm_nt<float, __hip_bfloat16><<<gg, 256, 0, stream>>>(x, Wi, bi, xp, M_DIM, C_DIM, C_DIM);
    mid_fused_v2<<<M_DIM / 4, 256, 0, stream>>>(x, dw_w, dw_b, ln_g, ln_b, Wo, bo, Wm, bm, xp, smp);
    gemm_nt<__hip_bfloat16, float><<<gg, 256, 0, stream>>>(smp, Wout, bout, out, M_DIM, C_DIM, C_DIM);
  }
}

// Round 6
// 208.770 us; speedup vs baseline: 1.4555x; 1.0204x over previous
//
#include <hip/hip_runtime.h>
#include <hip/hip_bf16.h>
#include <cstdint>

#define C_DIM 1024
#define L_DIM 2048
#define N_DIM 4
#define M_DIM (N_DIM * L_DIM)   // 8192

typedef __attribute__((ext_vector_type(8))) short frag8;    // 8 bf16 = 4 VGPRs
typedef __attribute__((ext_vector_type(4)))  float f32x4;
typedef __attribute__((ext_vector_type(16))) float f32x16;

// ---------------- helpers ----------------
__device__ __forceinline__ void gl_lds16(const void* g, void* l) {
  __builtin_amdgcn_global_load_lds((const __attribute__((address_space(1))) void*)g,
                                   (__attribute__((address_space(3))) void*)l,
                                   16, 0, 0);
}
__device__ __forceinline__ void store_out(float* Y, size_t idx, float v) { Y[idx] = v; }
__device__ __forceinline__ void store_out(__hip_bfloat16* Y, size_t idx, float v) {
  Y[idx] = __float2bfloat16(v);
}
__device__ __forceinline__ float4 ldbf4(const __hip_bfloat16* p) {
  union { short4 s; __hip_bfloat16 h[4]; } u; u.s = *(const short4*)p;
  return make_float4((float)u.h[0], (float)u.h[1], (float)u.h[2], (float)u.h[3]);
}
__device__ __forceinline__ void stbf4(__hip_bfloat16* p, float4 v) {
  union { short4 s; __hip_bfloat16 h[4]; } u;
  u.h[0] = __float2bfloat16(v.x); u.h[1] = __float2bfloat16(v.y);
  u.h[2] = __float2bfloat16(v.z); u.h[3] = __float2bfloat16(v.w);
  *(short4*)p = u.s;
}
// fast GELU: 0.5t(1+tanh(0.79788456(t+0.044715t^3))) == t / (1+exp(-2s))
__device__ __forceinline__ float gelu_fast(float t) {
  const float t3 = t * t * t;
  const float ns = -1.5957691216f * t - 0.0713548163f * t3;   // -2s
  return t / (1.f + __expf(ns));
}

// fp32 -> bf16 bulk convert, 8 elems/thread
__global__ __launch_bounds__(256)
void cvt_f32_bf16(const float* __restrict__ in, __hip_bfloat16* __restrict__ out, int n8) {
  const int i = blockIdx.x * 256 + threadIdx.x;
  if (i >= n8) return;
  const float4 a = *(const float4*)(in + (size_t)i * 8);
  const float4 b = *(const float4*)(in + (size_t)i * 8 + 4);
  union { __hip_bfloat16 h[8]; int4 q; } u;
  u.h[0] = __float2bfloat16(a.x); u.h[1] = __float2bfloat16(a.y);
  u.h[2] = __float2bfloat16(a.z); u.h[3] = __float2bfloat16(a.w);
  u.h[4] = __float2bfloat16(b.x); u.h[5] = __float2bfloat16(b.y);
  u.h[6] = __float2bfloat16(b.z); u.h[7] = __float2bfloat16(b.w);
  *(int4*)(out + (size_t)i * 8) = u.q;
}

// ---------------- GEMM: 32x32x16 MFMA, global_load_lds staging (m97 path) ------
// Y[M,N] = X[M,K] @ W[N,K]^T + bias. 128x128 tile, BK=32, 256 threads, 4 waves
// each owning a 64x64 quadrant as 2x2 of 32x32 tiles.
template <typename TY>
__global__ __launch_bounds__(256, 2)
void gemm_lds32(const __hip_bfloat16* __restrict__ X,
                const __hip_bfloat16* __restrict__ W,
                const float* __restrict__ bias,
                TY* __restrict__ Y, int M, int N, int K)
{
  __shared__ __hip_bfloat16 As[128 * 32];
  __shared__ __hip_bfloat16 Bs[128 * 32];
  const int tid  = threadIdx.x;
  const int lane = tid & 63;
  const int wave = tid >> 6;
  const int bm = blockIdx.x * 128;
  const int bn = blockIdx.y * 128;
  const int wr = (wave >> 1) * 64;
  const int wc = (wave & 1) * 64;
  const int srow  = tid >> 2;
  const int skoff = (tid & 3) * 8;

  f32x16 acc[2][2] = {};
  const __hip_bfloat16* gA0 = X + (size_t)(bm + srow) * K + skoff;
  const __hip_bfloat16* gA1 = X + (size_t)(bm + 64 + srow) * K + skoff;
  const __hip_bfloat16* gB0 = W + (size_t)(bn + srow) * K + skoff;
  const __hip_bfloat16* gB1 = W + (size_t)(bn + 64 + srow) * K + skoff;

  const int arow  = lane & 31;          // m (or n) within 32-tile
  const int akoff = (lane >> 5) * 8;    // k fragment base within a K=16 half

  for (int k0 = 0; k0 < K; k0 += 32) {
    gl_lds16(gA0 + k0, &As[tid * 8]);   // dest byte = tid*16 (wave-uniform + lane*16)
    gl_lds16(gA1 + k0, &As[2048 + tid * 8]);
    gl_lds16(gB0 + k0, &Bs[tid * 8]);
    gl_lds16(gB1 + k0, &Bs[2048 + tid * 8]);
    __syncthreads();

    frag8 a[2][2], b[2][2];
#pragma unroll
    for (int i = 0; i < 2; i++)
#pragma unroll
      for (int h = 0; h < 2; h++) {
        a[i][h] = *(const frag8*)&As[(wr + i * 32 + arow) * 32 + h * 16 + akoff];
        b[i][h] = *(const frag8*)&Bs[(wc + i * 32 + arow) * 32 + h * 16 + akoff];
      }
#pragma unroll
    for (int h = 0; h < 2; h++)
#pragma unroll
      for (int i = 0; i < 2; i++)
#pragma unroll
        for (int j = 0; j < 2; j++)
          acc[i][j] = __builtin_amdgcn_mfma_f32_32x32x16_bf16(a[i][h], b[j][h], acc[i][j], 0, 0, 0);
    __syncthreads();
  }

  // C/D layout (32x32): col=lane&31, row=(r&3)+8*(r>>2)+4*(lane>>5)  [m74/m101]
#pragma unroll
  for (int i = 0; i < 2; i++)
#pragma unroll
    for (int j = 0; j < 2; j++) {
      const int col = bn + wc + j * 32 + (lane & 31);
      const float bv = bias[col];
#pragma unroll
      for (int r = 0; r < 16; r++) {
        const int row = bm + wr + i * 32 + (r & 3) + 8 * (r >> 2) + 4 * (lane >> 5);
        store_out(Y, (size_t)row * N + col, acc[i][j][r] + bv);
      }
    }
}

// ---------------- fallback GEMM (16x16, register staging) ----------------
struct Ld8f { float4 a, b; };
struct Ld8b { int4 a; };
__device__ __forceinline__ Ld8f ld8(const float* p) {
  return { *(const float4*)p, *(const float4*)(p + 4) };
}
__device__ __forceinline__ Ld8b ld8(const __hip_bfloat16* p) { return { *(const int4*)p }; }
__device__ __forceinline__ void st8(__hip_bfloat16* l, const Ld8f& v) {
  union { __hip_bfloat16 h[8]; int4 q; } u;
  u.h[0] = __float2bfloat16(v.a.x); u.h[1] = __float2bfloat16(v.a.y);
  u.h[2] = __float2bfloat16(v.a.z); u.h[3] = __float2bfloat16(v.a.w);
  u.h[4] = __float2bfloat16(v.b.x); u.h[5] = __float2bfloat16(v.b.y);
  u.h[6] = __float2bfloat16(v.b.z); u.h[7] = __float2bfloat16(v.b.w);
  *(int4*)l = u.q;
}
__device__ __forceinline__ void st8(__hip_bfloat16* l, const Ld8b& v) { *(int4*)l = v.a; }

template <typename TX, typename TY>
__global__ __launch_bounds__(256, 2)
void gemm_nt(const TX* __restrict__ X, const float* __restrict__ W,
             const float* __restrict__ bias, TY* __restrict__ Y, int M, int N, int K)
{
  __shared__ __hip_bfloat16 As[128 * 32];
  __shared__ __hip_bfloat16 Bs[128 * 32];
  const int tid  = threadIdx.x;
  const int lane = tid & 63;
  const int wave = tid >> 6;
  const int bm = blockIdx.x * 128;
  const int bn = blockIdx.y * 128;
  const int wr = (wave >> 1) * 64;
  const int wc = (wave & 1) * 64;
  const int srow  = tid >> 2;
  const int skoff = (tid & 3) * 8;

  f32x4 acc[4][4] = {};
  const TX*    gA0 = X + (size_t)(bm + srow) * K + skoff;
  const TX*    gA1 = X + (size_t)(bm + 64 + srow) * K + skoff;
  const float* gB0 = W + (size_t)(bn + srow) * K + skoff;
  const float* gB1 = W + (size_t)(bn + 64 + srow) * K + skoff;
  const int arow  = lane & 15;
  const int akoff = (lane >> 4) * 8;

  for (int k0 = 0; k0 < K; k0 += 32) {
    const auto va0 = ld8(gA0 + k0);
    const auto va1 = ld8(gA1 + k0);
    const auto vb0 = ld8(gB0 + k0);
    const auto vb1 = ld8(gB1 + k0);
    __syncthreads();
    st8(&As[srow * 32 + skoff],        va0);
    st8(&As[(64 + srow) * 32 + skoff], va1);
    st8(&Bs[srow * 32 + skoff],        vb0);
    st8(&Bs[(64 + srow) * 32 + skoff], vb1);
    __syncthreads();

    frag8 a[4], b[4];
#pragma unroll
    for (int i = 0; i < 4; i++)
      a[i] = *(const frag8*)&As[(wr + i * 16 + arow) * 32 + akoff];
#pragma unroll
    for (int j = 0; j < 4; j++)
      b[j] = *(const frag8*)&Bs[(wc + j * 16 + arow) * 32 + akoff];
#pragma unroll
    for (int i = 0; i < 4; i++)
#pragma unroll
      for (int j = 0; j < 4; j++)
        acc[i][j] = __builtin_amdgcn_mfma_f32_16x16x32_bf16(a[i], b[j], acc[i][j], 0, 0, 0);
  }
#pragma unroll
  for (int i = 0; i < 4; i++)
#pragma unroll
    for (int j = 0; j < 4; j++) {
      const int col = bn + wc + j * 16 + (lane & 15);
      const float bv = bias[col];
#pragma unroll
      for (int r = 0; r < 4; r++) {
        const int row = bm + wr + i * 16 + (lane >> 4) * 4 + r;
        store_out(Y, (size_t)row * N + col, acc[i][j][r] + bv);
      }
    }
}

// ---------------- mid v3: 2 rows per WAVE, shared loads, no barriers ----------------
__global__ __launch_bounds__(256)
void mid_fused_v3(const float* __restrict__ x,
                  const float* __restrict__ dw_w, const float* __restrict__ dw_b,
                  const float* __restrict__ ln_g, const float* __restrict__ ln_b,
                  const float* __restrict__ Wo,   const float* __restrict__ bo,
                  const float* __restrict__ Wm,   const float* __restrict__ bmb,
                  const __hip_bfloat16* __restrict__ xp,
                  __hip_bfloat16* __restrict__ smp)
{
  // 1024 blocks; XCD round-robin heuristic: each XCD gets a contiguous 1024-row span.
  const int b    = blockIdx.x;
  const int bs   = (b & 7) * 128 + (b >> 3);
  const int wid  = threadIdx.x >> 6;
  const int lane = threadIdx.x & 63;
  const int row0 = bs * 8 + wid * 2;            // even; row1 = row0+1 (same n)
  const int l0   = row0 & (L_DIM - 1);
  const int n    = row0 >> 11;

  const float* xb = x + ((size_t)n * L_DIM) * C_DIM;

  // dwconv for rows l0, l0+1 sharing x-rows {l0-1, l0, l0+1, l0+2}
  float4 v0[4], v1[4];
#pragma unroll
  for (int j = 0; j < 4; j++) {
    const int c4 = j * 256 + lane * 4;
    float4 xa = make_float4(0.f, 0.f, 0.f, 0.f);
    float4 xd = make_float4(0.f, 0.f, 0.f, 0.f);
    if (l0 > 0)              xa = *(const float4*)(xb + (size_t)(l0 - 1) * C_DIM + c4);
    const float4 xm = *(const float4*)(xb + (size_t)l0 * C_DIM + c4);
    const float4 xc = *(const float4*)(xb + (size_t)(l0 + 1) * C_DIM + c4);
    if (l0 + 2 <= L_DIM - 1) xd = *(const float4*)(xb + (size_t)(l0 + 2) * C_DIM + c4);
    const float4 w0 = *(const float4*)(dw_w + (size_t)c4 * 3);
    const float4 w1 = *(const float4*)(dw_w + (size_t)c4 * 3 + 4);
    const float4 w2 = *(const float4*)(dw_w + (size_t)c4 * 3 + 8);
    const float4 bb = *(const float4*)(dw_b + c4);
    // channel taps: ch0:(w0.x,w0.y,w0.z) ch1:(w0.w,w1.x,w1.y) ch2:(w1.z,w1.w,w2.x) ch3:(w2.y,w2.z,w2.w)
    v0[j].x = xa.x * w0.x + xm.x * w0.y + xc.x * w0.z + bb.x;
    v0[j].y = xa.y * w0.w + xm.y * w1.x + xc.y * w1.y + bb.y;
    v0[j].z = xa.z * w1.z + xm.z * w1.w + xc.z * w2.x + bb.z;
    v0[j].w = xa.w * w2.y + xm.w * w2.z + xc.w * w2.w + bb.w;
    v1[j].x = xm.x * w0.x + xc.x * w0.y + xd.x * w0.z + bb.x;
    v1[j].y = xm.y * w0.w + xc.y * w1.x + xd.y * w1.y + bb.y;
    v1[j].z = xm.z * w1.z + xc.z * w1.w + xd.z * w2.x + bb.z;
    v1[j].w = xm.w * w2.y + xc.w * w2.z + xd.w * w2.w + bb.w;
  }

  // LayerNorm stats (butterfly -> all lanes)
  float a1 = 0.f, a2 = 0.f, b1 = 0.f, b2 = 0.f;
#pragma unroll
  for (int j = 0; j < 4; j++) {
    a1 += v0[j].x + v0[j].y + v0[j].z + v0[j].w;
    a2 += v0[j].x * v0[j].x + v0[j].y * v0[j].y + v0[j].z * v0[j].z + v0[j].w * v0[j].w;
    b1 += v1[j].x + v1[j].y + v1[j].z + v1[j].w;
    b2 += v1[j].x * v1[j].x + v1[j].y * v1[j].y + v1[j].z * v1[j].z + v1[j].w * v1[j].w;
  }
#pragma unroll
  for (int m = 1; m < 64; m <<= 1) {
    a1 += __shfl_xor(a1, m); a2 += __shfl_xor(a2, m);
    b1 += __shfl_xor(b1, m); b2 += __shfl_xor(b2, m);
  }
  const float mu0 = a1 * (1.f / C_DIM), mu1 = b1 * (1.f / C_DIM);
  const float rstd0 = rsqrtf(a2 * (1.f / C_DIM) - mu0 * mu0 + 1e-5f);
  const float rstd1 = rsqrtf(b2 * (1.f / C_DIM) - mu1 * mu1 + 1e-5f);

  // LN + GELU (fast), in place
#pragma unroll
  for (int j = 0; j < 4; j++) {
    const int c4 = j * 256 + lane * 4;
    const float4 gg = *(const float4*)(ln_g + c4);
    const float4 bb = *(const float4*)(ln_b + c4);
    v0[j].x = gelu_fast((v0[j].x - mu0) * rstd0 * gg.x + bb.x);
    v0[j].y = gelu_fast((v0[j].y - mu0) * rstd0 * gg.y + bb.y);
    v0[j].z = gelu_fast((v0[j].z - mu0) * rstd0 * gg.z + bb.z);
    v0[j].w = gelu_fast((v0[j].w - mu0) * rstd0 * gg.w + bb.w);
    v1[j].x = gelu_fast((v1[j].x - mu1) * rstd1 * gg.x + bb.x);
    v1[j].y = gelu_fast((v1[j].y - mu1) * rstd1 * gg.y + bb.y);
    v1[j].z = gelu_fast((v1[j].z - mu1) * rstd1 * gg.z + bb.z);
    v1[j].w = gelu_fast((v1[j].w - mu1) * rstd1 * gg.w + bb.w);
  }

  // head dot-products, Wo/Wm loaded once for both rows
  float po[2][7] = {}, pm[2][7] = {};
#pragma unroll
  for (int k = 0; k < 7; k++) {
#pragma unroll
    for (int j = 0; j < 4; j++) {
      const int c4 = j * 256 + lane * 4;
      const float4 wo = *(const float4*)(Wo + (size_t)k * C_DIM + c4);
      const float4 wm = *(const float4*)(Wm + (size_t)k * C_DIM + c4);
      po[0][k] += v0[j].x * wo.x + v0[j].y * wo.y + v0[j].z * wo.z + v0[j].w * wo.w;
      pm[0][k] += v0[j].x * wm.x + v0[j].y * wm.y + v0[j].z * wm.z + v0[j].w * wm.w;
      po[1][k] += v1[j].x * wo.x + v1[j].y * wo.y + v1[j].z * wo.z + v1[j].w * wo.w;
      pm[1][k] += v1[j].x * wm.x + v1[j].y * wm.y + v1[j].z * wm.z + v1[j].w * wm.w;
    }
  }
#pragma unroll
  for (int rr = 0; rr < 2; rr++)
#pragma unroll
    for (int k = 0; k < 7; k++)
#pragma unroll
      for (int m = 1; m < 64; m <<= 1) {
        po[rr][k] += __shfl_xor(po[rr][k], m);
        pm[rr][k] += __shfl_xor(pm[rr][k], m);
      }

  // per-row: softmax, sampling weights, gather (every lane redundantly computes weights)
  const __hip_bfloat16* xpn = xp + ((size_t)n * L_DIM) * C_DIM;
#pragma unroll
  for (int rr = 0; rr < 2; rr++) {
    const int l = l0 + rr;
    float lg[7], mx = -1e30f;
#pragma unroll
    for (int k = 0; k < 7; k++) { lg[k] = pm[rr][k] + bmb[k]; mx = fmaxf(mx, lg[k]); }
    float se = 0.f, e[7];
#pragma unroll
    for (int k = 0; k < 7; k++) { e[k] = __expf(lg[k] - mx); se += e[k]; }
    const float inv = 1.f / se;

    float wf[7], wcl[7]; int pf[7], pc[7];
#pragma unroll
    for (int k = 0; k < 7; k++) {
      const float msk = e[k] * inv;
      const float off = (po[rr][k] + bo[k]) * 2.0f;
      const float ap  = (float)l + (float)(k - 3) + off;
      const float apc = fminf(fmaxf(ap, 0.f), (float)(L_DIM - 1));
      int f = (int)apc;
      int c = f + 1; if (c > L_DIM - 1) c = L_DIM - 1;
      const float w1  = apc - (float)f;
      const float val = (ap < 0.f || ap > (float)(L_DIM - 1)) ? 0.f : 1.f;
      wf[k]  = (1.f - w1) * val * msk;
      wcl[k] = w1 * val * msk;
      pf[k] = f; pc[k] = c;
    }

    __hip_bfloat16* so = smp + (size_t)(row0 + rr) * C_DIM;
#pragma unroll
    for (int j = 0; j < 4; j++) {
      const int c4 = j * 256 + lane * 4;
      float4 acc = make_float4(0.f, 0.f, 0.f, 0.f);
#pragma unroll
      for (int k = 0; k < 7; k++) {
        const float4 vf = ldbf4(xpn + (size_t)pf[k] * C_DIM + c4);
        const float4 vc = ldbf4(xpn + (size_t)pc[k] * C_DIM + c4);
        acc.x += wf[k] * vf.x + wcl[k] * vc.x;
        acc.y += wf[k] * vf.y + wcl[k] * vc.y;
        acc.z += wf[k] * vf.z + wcl[k] * vc.z;
        acc.w += wf[k] * vf.w + wcl[k] * vc.w;
      }
      stbf4(so + c4, acc);
    }
  }
}

// ---------------- host ----------------
extern "C" void kernel_launch(void* const* d_in, const int* in_sizes, int n_in,
                              void* d_out, int out_size, void* d_ws, size_t ws_size,
                              hipStream_t stream)
{
  const float* x    = (const float*)d_in[0];
  const float* Wi   = (const float*)d_in[1];
  const float* bi   = (const float*)d_in[2];
  const float* dw_w = (const float*)d_in[3];
  const float* dw_b = (const float*)d_in[4];
  const float* ln_g = (const float*)d_in[5];
  const float* ln_b = (const float*)d_in[6];
  const float* Wo   = (const float*)d_in[7];
  const float* bo   = (const float*)d_in[8];
  const float* Wm   = (const float*)d_in[9];
  const float* bm   = (const float*)d_in[10];
  const float* Wout = (const float*)d_in[11];
  const float* bout = (const float*)d_in[12];
  float* out = (float*)d_out;

  const size_t XE = (size_t)M_DIM * C_DIM;
  const size_t WE = (size_t)C_DIM * C_DIM;
  char* wsb = (char*)d_ws;
  __hip_bfloat16* xp    = (__hip_bfloat16*)wsb;
  __hip_bfloat16* smp   = (__hip_bfloat16*)(wsb + XE * 2);
  __hip_bfloat16* Wib   = (__hip_bfloat16*)(wsb + XE * 4);
  __hip_bfloat16* Woutb = (__hip_bfloat16*)(wsb + XE * 4 + WE * 2);
  __hip_bfloat16* xbb   = (__hip_bfloat16*)(wsb + XE * 4 + WE * 4);

  const size_t need_w2   = XE * 4 + WE * 4;
  const size_t need_full = need_w2 + XE * 2;

  dim3 gg(M_DIM / 128, C_DIM / 128);   // 64 x 8

  if (ws_size >= need_full) {
    cvt_f32_bf16<<<(int)(XE / 8 / 256), 256, 0, stream>>>(x, xbb, (int)(XE / 8));
    cvt_f32_bf16<<<(int)(WE / 8 / 256), 256, 0, stream>>>(Wi, Wib, (int)(WE / 8));
    cvt_f32_bf16<<<(int)(WE / 8 / 256), 256, 0, stream>>>(Wout, Woutb, (int)(WE / 8));
    gemm_lds32<__hip_bfloat16><<<gg, 256, 0, stream>>>(xbb, Wib, bi, xp, M_DIM, C_DIM, C_DIM);
    mid_fused_v3<<<M_DIM / 8, 256, 0, stream>>>(x, dw_w, dw_b, ln_g, ln_b, Wo, bo, Wm, bm, xp, smp);
    gemm_lds32<float><<<gg, 256, 0, stream>>>(smp, Woutb, bout, out, M_DIM, C_DIM, C_DIM);
  } else if (ws_size >= need_w2) {
    cvt_f32_bf16<<<(int)(WE / 8 / 256), 256, 0, stream>>>(Wout, Woutb, (int)(WE / 8));
    gemm_nt<float, __hip_bfloat16><<<gg, 256, 0, stream>>>(x, Wi, bi, xp, M_DIM, C_DIM, C_DIM);
    mid_fused_v3<<<M_DIM / 8, 256, 0, stream>>>(x, dw_w, dw_b, ln_g, ln_b, Wo, bo, Wm, bm, xp, smp);
    gemm_lds32<float><<<gg, 256, 0, stream>>>(smp, Woutb, bout, out, M_DIM, C_DIM, C_DIM);
  } else {
    gemm_nt<float, __hip_bfloat16><<<gg, 256, 0, stream>>>(x, Wi, bi, xp, M_DIM, C_DIM, C_DIM);
    mid_fused_v3<<<M_DIM / 8, 256, 0, stream>>>(x, dw_w, dw_b, ln_g, ln_b, Wo, bo, Wm, bm, xp, smp);
    gemm_nt<__hip_bfloat16, float><<<gg, 256, 0, stream>>>(smp, Wout, bout, out, M_DIM, C_DIM, C_DIM);
  }
}

// Round 7
// 205.688 us; speedup vs baseline: 1.4773x; 1.0150x over previous
//
#include <hip/hip_runtime.h>
#include <hip/hip_bf16.h>
#include <cstdint>

#define C_DIM 1024
#define L_DIM 2048
#define N_DIM 4
#define M_DIM (N_DIM * L_DIM)   // 8192

typedef __attribute__((ext_vector_type(8))) short frag8;    // 8 bf16 = 4 VGPRs
typedef __attribute__((ext_vector_type(4)))  float f32x4;
typedef __attribute__((ext_vector_type(16))) float f32x16;

// ---------------- helpers ----------------
__device__ __forceinline__ void gl_lds16(const void* g, void* l) {
  __builtin_amdgcn_global_load_lds((const __attribute__((address_space(1))) void*)g,
                                   (__attribute__((address_space(3))) void*)l,
                                   16, 0, 0);
}
__device__ __forceinline__ void store_out(float* Y, size_t idx, float v) { Y[idx] = v; }
__device__ __forceinline__ void store_out(__hip_bfloat16* Y, size_t idx, float v) {
  Y[idx] = __float2bfloat16(v);
}
__device__ __forceinline__ float4 ldbf4(const __hip_bfloat16* p) {
  union { short4 s; __hip_bfloat16 h[4]; } u; u.s = *(const short4*)p;
  return make_float4((float)u.h[0], (float)u.h[1], (float)u.h[2], (float)u.h[3]);
}
__device__ __forceinline__ void stbf4(__hip_bfloat16* p, float4 v) {
  union { short4 s; __hip_bfloat16 h[4]; } u;
  u.h[0] = __float2bfloat16(v.x); u.h[1] = __float2bfloat16(v.y);
  u.h[2] = __float2bfloat16(v.z); u.h[3] = __float2bfloat16(v.w);
  *(short4*)p = u.s;
}
// fast GELU (tanh form): t / (1+exp(-2*(0.79788456(t+0.044715 t^3))))
__device__ __forceinline__ float gelu_fast(float t) {
  const float t3 = t * t * t;
  const float ns = -1.5957691216f * t - 0.0713548163f * t3;
  return t / (1.f + __expf(ns));
}

// fp32 -> bf16 bulk convert, 8 elems/thread
__global__ __launch_bounds__(256)
void cvt_f32_bf16(const float* __restrict__ in, __hip_bfloat16* __restrict__ out, int n8) {
  const int i = blockIdx.x * 256 + threadIdx.x;
  if (i >= n8) return;
  const float4 a = *(const float4*)(in + (size_t)i * 8);
  const float4 b = *(const float4*)(in + (size_t)i * 8 + 4);
  union { __hip_bfloat16 h[8]; int4 q; } u;
  u.h[0] = __float2bfloat16(a.x); u.h[1] = __float2bfloat16(a.y);
  u.h[2] = __float2bfloat16(a.z); u.h[3] = __float2bfloat16(a.w);
  u.h[4] = __float2bfloat16(b.x); u.h[5] = __float2bfloat16(b.y);
  u.h[6] = __float2bfloat16(b.z); u.h[7] = __float2bfloat16(b.w);
  *(int4*)(out + (size_t)i * 8) = u.q;
}

// ------- GEMM: BK=64, double-buffered LDS, 32x32x16 MFMA, 1 barrier/iter -------
// Y[M,N] = X[M,K] @ W[N,K]^T + bias. 128x128 tile, 256 threads, 4 waves (64x64 each).
// LDS: 2 buffers x (A,B) x 2 K-panels of [128 rows x 32 elems] = 64 KB.
// Each panel stage is exactly the m97 pattern (dest byte = tid*16).
template <typename TY>
__global__ __launch_bounds__(256, 2)
void gemm_db(const __hip_bfloat16* __restrict__ X,
             const __hip_bfloat16* __restrict__ W,
             const float* __restrict__ bias,
             TY* __restrict__ Y, int M, int N, int K)
{
  __shared__ __hip_bfloat16 As[2][2][128 * 32];   // [buf][panel]
  __shared__ __hip_bfloat16 Bs[2][2][128 * 32];
  const int tid  = threadIdx.x;
  const int lane = tid & 63;
  const int wave = tid >> 6;
  const int bm = blockIdx.x * 128;
  const int bn = blockIdx.y * 128;
  const int wr = (wave >> 1) * 64;
  const int wc = (wave & 1) * 64;
  const int srow  = tid >> 2;       // 0..63
  const int skoff = (tid & 3) * 8;  // elements

  const __hip_bfloat16* gA0 = X + (size_t)(bm + srow) * K + skoff;
  const __hip_bfloat16* gA1 = X + (size_t)(bm + 64 + srow) * K + skoff;
  const __hip_bfloat16* gB0 = W + (size_t)(bn + srow) * K + skoff;
  const __hip_bfloat16* gB1 = W + (size_t)(bn + 64 + srow) * K + skoff;

  f32x16 acc[2][2] = {};
  const int arow  = lane & 31;
  const int akoff = (lane >> 5) * 8;

#define STAGE(k0, buf)                                        \
  do {                                                        \
    gl_lds16(gA0 + (k0),      &As[buf][0][tid * 8]);          \
    gl_lds16(gA1 + (k0),      &As[buf][0][2048 + tid * 8]);   \
    gl_lds16(gA0 + (k0) + 32, &As[buf][1][tid * 8]);          \
    gl_lds16(gA1 + (k0) + 32, &As[buf][1][2048 + tid * 8]);   \
    gl_lds16(gB0 + (k0),      &Bs[buf][0][tid * 8]);          \
    gl_lds16(gB1 + (k0),      &Bs[buf][0][2048 + tid * 8]);   \
    gl_lds16(gB0 + (k0) + 32, &Bs[buf][1][tid * 8]);          \
    gl_lds16(gB1 + (k0) + 32, &Bs[buf][1][2048 + tid * 8]);   \
  } while (0)

  STAGE(0, 0);
  __syncthreads();
  const int iters = K / 64;
  for (int it = 0; it < iters; ++it) {
    const int cur = it & 1;
    if (it + 1 < iters) STAGE((it + 1) * 64, cur ^ 1);   // prefetch next tile

#pragma unroll
    for (int p = 0; p < 2; ++p)
#pragma unroll
      for (int h = 0; h < 2; ++h) {
        const frag8 a0 = *(const frag8*)&As[cur][p][(wr + arow) * 32 + h * 16 + akoff];
        const frag8 a1 = *(const frag8*)&As[cur][p][(wr + 32 + arow) * 32 + h * 16 + akoff];
        const frag8 b0 = *(const frag8*)&Bs[cur][p][(wc + arow) * 32 + h * 16 + akoff];
        const frag8 b1 = *(const frag8*)&Bs[cur][p][(wc + 32 + arow) * 32 + h * 16 + akoff];
        acc[0][0] = __builtin_amdgcn_mfma_f32_32x32x16_bf16(a0, b0, acc[0][0], 0, 0, 0);
        acc[0][1] = __builtin_amdgcn_mfma_f32_32x32x16_bf16(a0, b1, acc[0][1], 0, 0, 0);
        acc[1][0] = __builtin_amdgcn_mfma_f32_32x32x16_bf16(a1, b0, acc[1][0], 0, 0, 0);
        acc[1][1] = __builtin_amdgcn_mfma_f32_32x32x16_bf16(a1, b1, acc[1][1], 0, 0, 0);
      }
    __syncthreads();   // drains prefetch loads + protects buf reuse
  }
#undef STAGE

  // C/D layout (32x32): col=lane&31, row=(r&3)+8*(r>>2)+4*(lane>>5)  [m74/m101]
#pragma unroll
  for (int i = 0; i < 2; i++)
#pragma unroll
    for (int j = 0; j < 2; j++) {
      const int col = bn + wc + j * 32 + (lane & 31);
      const float bv = bias[col];
#pragma unroll
      for (int r = 0; r < 16; r++) {
        const int row = bm + wr + i * 32 + (r & 3) + 8 * (r >> 2) + 4 * (lane >> 5);
        store_out(Y, (size_t)row * N + col, acc[i][j][r] + bv);
      }
    }
}

// ---------------- fallback GEMM (16x16, register staging) ----------------
struct Ld8f { float4 a, b; };
struct Ld8b { int4 a; };
__device__ __forceinline__ Ld8f ld8(const float* p) {
  return { *(const float4*)p, *(const float4*)(p + 4) };
}
__device__ __forceinline__ Ld8b ld8(const __hip_bfloat16* p) { return { *(const int4*)p }; }
__device__ __forceinline__ void st8(__hip_bfloat16* l, const Ld8f& v) {
  union { __hip_bfloat16 h[8]; int4 q; } u;
  u.h[0] = __float2bfloat16(v.a.x); u.h[1] = __float2bfloat16(v.a.y);
  u.h[2] = __float2bfloat16(v.a.z); u.h[3] = __float2bfloat16(v.a.w);
  u.h[4] = __float2bfloat16(v.b.x); u.h[5] = __float2bfloat16(v.b.y);
  u.h[6] = __float2bfloat16(v.b.z); u.h[7] = __float2bfloat16(v.b.w);
  *(int4*)l = u.q;
}
__device__ __forceinline__ void st8(__hip_bfloat16* l, const Ld8b& v) { *(int4*)l = v.a; }

template <typename TX, typename TY>
__global__ __launch_bounds__(256, 2)
void gemm_nt(const TX* __restrict__ X, const float* __restrict__ W,
             const float* __restrict__ bias, TY* __restrict__ Y, int M, int N, int K)
{
  __shared__ __hip_bfloat16 As[128 * 32];
  __shared__ __hip_bfloat16 Bs[128 * 32];
  const int tid  = threadIdx.x;
  const int lane = tid & 63;
  const int wave = tid >> 6;
  const int bm = blockIdx.x * 128;
  const int bn = blockIdx.y * 128;
  const int wr = (wave >> 1) * 64;
  const int wc = (wave & 1) * 64;
  const int srow  = tid >> 2;
  const int skoff = (tid & 3) * 8;

  f32x4 acc[4][4] = {};
  const TX*    gA0 = X + (size_t)(bm + srow) * K + skoff;
  const TX*    gA1 = X + (size_t)(bm + 64 + srow) * K + skoff;
  const float* gB0 = W + (size_t)(bn + srow) * K + skoff;
  const float* gB1 = W + (size_t)(bn + 64 + srow) * K + skoff;
  const int arow  = lane & 15;
  const int akoff = (lane >> 4) * 8;

  for (int k0 = 0; k0 < K; k0 += 32) {
    const auto va0 = ld8(gA0 + k0);
    const auto va1 = ld8(gA1 + k0);
    const auto vb0 = ld8(gB0 + k0);
    const auto vb1 = ld8(gB1 + k0);
    __syncthreads();
    st8(&As[srow * 32 + skoff],        va0);
    st8(&As[(64 + srow) * 32 + skoff], va1);
    st8(&Bs[srow * 32 + skoff],        vb0);
    st8(&Bs[(64 + srow) * 32 + skoff], vb1);
    __syncthreads();

    frag8 a[4], b[4];
#pragma unroll
    for (int i = 0; i < 4; i++)
      a[i] = *(const frag8*)&As[(wr + i * 16 + arow) * 32 + akoff];
#pragma unroll
    for (int j = 0; j < 4; j++)
      b[j] = *(const frag8*)&Bs[(wc + j * 16 + arow) * 32 + akoff];
#pragma unroll
    for (int i = 0; i < 4; i++)
#pragma unroll
      for (int j = 0; j < 4; j++)
        acc[i][j] = __builtin_amdgcn_mfma_f32_16x16x32_bf16(a[i], b[j], acc[i][j], 0, 0, 0);
  }
#pragma unroll
  for (int i = 0; i < 4; i++)
#pragma unroll
    for (int j = 0; j < 4; j++) {
      const int col = bn + wc + j * 16 + (lane & 15);
      const float bv = bias[col];
#pragma unroll
      for (int r = 0; r < 4; r++) {
        const int row = bm + wr + i * 16 + (lane >> 4) * 4 + r;
        store_out(Y, (size_t)row * N + col, acc[i][j][r] + bv);
      }
    }
}

// ------- mid v4: one WAVE per row (v2 structure, proven 53us) + gelu_fast -------
__global__ __launch_bounds__(256)
void mid_fused_v4(const float* __restrict__ x,
                  const float* __restrict__ dw_w, const float* __restrict__ dw_b,
                  const float* __restrict__ ln_g, const float* __restrict__ ln_b,
                  const float* __restrict__ Wo,   const float* __restrict__ bo,
                  const float* __restrict__ Wm,   const float* __restrict__ bmb,
                  const __hip_bfloat16* __restrict__ xp,
                  __hip_bfloat16* __restrict__ smp)
{
  const int b    = blockIdx.x;                 // 2048 blocks
  const int bs   = (b & 7) * 256 + (b >> 3);   // XCD-contiguous row spans
  const int wid  = threadIdx.x >> 6;
  const int lane = threadIdx.x & 63;
  const int row  = bs * 4 + wid;
  const int l    = row & (L_DIM - 1);
  const int n    = row >> 11;

  const float* xr = x + (size_t)row * C_DIM;

  float4 v[4];
#pragma unroll
  for (int j = 0; j < 4; j++) {
    const int c4 = j * 256 + lane * 4;
    const float4 x0 = *(const float4*)(xr + c4);
    float4 xm = make_float4(0.f, 0.f, 0.f, 0.f);
    float4 xq = make_float4(0.f, 0.f, 0.f, 0.f);
    if (l > 0)         xm = *(const float4*)(xr + c4 - C_DIM);
    if (l < L_DIM - 1) xq = *(const float4*)(xr + c4 + C_DIM);
    const float4 w0 = *(const float4*)(dw_w + (size_t)c4 * 3);
    const float4 w1 = *(const float4*)(dw_w + (size_t)c4 * 3 + 4);
    const float4 w2 = *(const float4*)(dw_w + (size_t)c4 * 3 + 8);
    const float4 bb = *(const float4*)(dw_b + c4);
    v[j].x = xm.x * w0.x + x0.x * w0.y + xq.x * w0.z + bb.x;
    v[j].y = xm.y * w0.w + x0.y * w1.x + xq.y * w1.y + bb.y;
    v[j].z = xm.z * w1.z + x0.z * w1.w + xq.z * w2.x + bb.z;
    v[j].w = xm.w * w2.y + x0.w * w2.z + xq.w * w2.w + bb.w;
  }

  float s1 = 0.f, s2 = 0.f;
#pragma unroll
  for (int j = 0; j < 4; j++) {
    s1 += v[j].x + v[j].y + v[j].z + v[j].w;
    s2 += v[j].x * v[j].x + v[j].y * v[j].y + v[j].z * v[j].z + v[j].w * v[j].w;
  }
#pragma unroll
  for (int m = 1; m < 64; m <<= 1) { s1 += __shfl_xor(s1, m); s2 += __shfl_xor(s2, m); }
  const float mu   = s1 * (1.f / C_DIM);
  const float rstd = rsqrtf(s2 * (1.f / C_DIM) - mu * mu + 1e-5f);

  float4 g[4];
#pragma unroll
  for (int j = 0; j < 4; j++) {
    const int c4 = j * 256 + lane * 4;
    const float4 gg = *(const float4*)(ln_g + c4);
    const float4 bb = *(const float4*)(ln_b + c4);
    g[j].x = gelu_fast((v[j].x - mu) * rstd * gg.x + bb.x);
    g[j].y = gelu_fast((v[j].y - mu) * rstd * gg.y + bb.y);
    g[j].z = gelu_fast((v[j].z - mu) * rstd * gg.z + bb.z);
    g[j].w = gelu_fast((v[j].w - mu) * rstd * gg.w + bb.w);
  }

  float po[7] = {0,0,0,0,0,0,0}, pm[7] = {0,0,0,0,0,0,0};
#pragma unroll
  for (int k = 0; k < 7; k++) {
#pragma unroll
    for (int j = 0; j < 4; j++) {
      const int c4 = j * 256 + lane * 4;
      const float4 wo = *(const float4*)(Wo + (size_t)k * C_DIM + c4);
      const float4 wm = *(const float4*)(Wm + (size_t)k * C_DIM + c4);
      po[k] += g[j].x * wo.x + g[j].y * wo.y + g[j].z * wo.z + g[j].w * wo.w;
      pm[k] += g[j].x * wm.x + g[j].y * wm.y + g[j].z * wm.z + g[j].w * wm.w;
    }
  }
#pragma unroll
  for (int k = 0; k < 7; k++)
#pragma unroll
    for (int m = 1; m < 64; m <<= 1) {
      po[k] += __shfl_xor(po[k], m);
      pm[k] += __shfl_xor(pm[k], m);
    }

  float lg[7], mx = -1e30f;
#pragma unroll
  for (int k = 0; k < 7; k++) { lg[k] = pm[k] + bmb[k]; mx = fmaxf(mx, lg[k]); }
  float se = 0.f, e[7];
#pragma unroll
  for (int k = 0; k < 7; k++) { e[k] = __expf(lg[k] - mx); se += e[k]; }
  const float inv = 1.f / se;

  float wf[7], wcl[7]; int pf[7], pc[7];
#pragma unroll
  for (int k = 0; k < 7; k++) {
    const float msk = e[k] * inv;
    const float off = (po[k] + bo[k]) * 2.0f;
    const float ap  = (float)l + (float)(k - 3) + off;
    const float apc = fminf(fmaxf(ap, 0.f), (float)(L_DIM - 1));
    int f = (int)apc;
    int c = f + 1; if (c > L_DIM - 1) c = L_DIM - 1;
    const float w1  = apc - (float)f;
    const float val = (ap < 0.f || ap > (float)(L_DIM - 1)) ? 0.f : 1.f;
    wf[k]  = (1.f - w1) * val * msk;
    wcl[k] = w1 * val * msk;
    pf[k] = f; pc[k] = c;
  }

  const __hip_bfloat16* xpn = xp + ((size_t)n * L_DIM) * C_DIM;
  __hip_bfloat16* so = smp + (size_t)row * C_DIM;
#pragma unroll
  for (int j = 0; j < 4; j++) {
    const int c4 = j * 256 + lane * 4;
    float4 a = make_float4(0.f, 0.f, 0.f, 0.f);
#pragma unroll
    for (int k = 0; k < 7; k++) {
      const float4 vf = ldbf4(xpn + (size_t)pf[k] * C_DIM + c4);
      const float4 vc = ldbf4(xpn + (size_t)pc[k] * C_DIM + c4);
      a.x += wf[k] * vf.x + wcl[k] * vc.x;
      a.y += wf[k] * vf.y + wcl[k] * vc.y;
      a.z += wf[k] * vf.z + wcl[k] * vc.z;
      a.w += wf[k] * vf.w + wcl[k] * vc.w;
    }
    stbf4(so + c4, a);
  }
}

// ---------------- host ----------------
extern "C" void kernel_launch(void* const* d_in, const int* in_sizes, int n_in,
                              void* d_out, int out_size, void* d_ws, size_t ws_size,
                              hipStream_t stream)
{
  const float* x    = (const float*)d_in[0];
  const float* Wi   = (const float*)d_in[1];
  const float* bi   = (const float*)d_in[2];
  const float* dw_w = (const float*)d_in[3];
  const float* dw_b = (const float*)d_in[4];
  const float* ln_g = (const float*)d_in[5];
  const float* ln_b = (const float*)d_in[6];
  const float* Wo   = (const float*)d_in[7];
  const float* bo   = (const float*)d_in[8];
  const float* Wm   = (const float*)d_in[9];
  const float* bm   = (const float*)d_in[10];
  const float* Wout = (const float*)d_in[11];
  const float* bout = (const float*)d_in[12];
  float* out = (float*)d_out;

  const size_t XE = (size_t)M_DIM * C_DIM;
  const size_t WE = (size_t)C_DIM * C_DIM;
  char* wsb = (char*)d_ws;
  __hip_bfloat16* xp    = (__hip_bfloat16*)wsb;
  __hip_bfloat16* smp   = (__hip_bfloat16*)(wsb + XE * 2);
  __hip_bfloat16* Wib   = (__hip_bfloat16*)(wsb + XE * 4);
  __hip_bfloat16* Woutb = (__hip_bfloat16*)(wsb + XE * 4 + WE * 2);
  __hip_bfloat16* xbb   = (__hip_bfloat16*)(wsb + XE * 4 + WE * 4);

  const size_t need_w2   = XE * 4 + WE * 4;
  const size_t need_full = need_w2 + XE * 2;

  dim3 gg(M_DIM / 128, C_DIM / 128);   // 64 x 8

  if (ws_size >= need_full) {
    cvt_f32_bf16<<<(int)(XE / 8 / 256), 256, 0, stream>>>(x, xbb, (int)(XE / 8));
    cvt_f32_bf16<<<(int)(WE / 8 / 256), 256, 0, stream>>>(Wi, Wib, (int)(WE / 8));
    cvt_f32_bf16<<<(int)(WE / 8 / 256), 256, 0, stream>>>(Wout, Woutb, (int)(WE / 8));
    gemm_db<__hip_bfloat16><<<gg, 256, 0, stream>>>(xbb, Wib, bi, xp, M_DIM, C_DIM, C_DIM);
    mid_fused_v4<<<M_DIM / 4, 256, 0, stream>>>(x, dw_w, dw_b, ln_g, ln_b, Wo, bo, Wm, bm, xp, smp);
    gemm_db<float><<<gg, 256, 0, stream>>>(smp, Woutb, bout, out, M_DIM, C_DIM, C_DIM);
  } else if (ws_size >= need_w2) {
    cvt_f32_bf16<<<(int)(WE / 8 / 256), 256, 0, stream>>>(Wout, Woutb, (int)(WE / 8));
    gemm_nt<float, __hip_bfloat16><<<gg, 256, 0, stream>>>(x, Wi, bi, xp, M_DIM, C_DIM, C_DIM);
    mid_fused_v4<<<M_DIM / 4, 256, 0, stream>>>(x, dw_w, dw_b, ln_g, ln_b, Wo, bo, Wm, bm, xp, smp);
    gemm_db<float><<<gg, 256, 0, stream>>>(smp, Woutb, bout, out, M_DIM, C_DIM, C_DIM);
  } else {
    gemm_nt<float, __hip_bfloat16><<<gg, 256, 0, stream>>>(x, Wi, bi, xp, M_DIM, C_DIM, C_DIM);
    mid_fused_v4<<<M_DIM / 4, 256, 0, stream>>>(x, dw_w, dw_b, ln_g, ln_b, Wo, bo, Wm, bm, xp, smp);
    gemm_nt<__hip_bfloat16, float><<<gg, 256, 0, stream>>>(smp, Wout, bout, out, M_DIM, C_DIM, C_DIM);
  }
}